// Round 1
// baseline (180.466 us; speedup 1.0000x reference)
//
#include <hip/hip_runtime.h>
#include <math.h>

// MS-SSIM on (16,1,512,512) fp32, 5 levels, 11x11 gaussian (sigma=1.5), 2x2 avg-pool.
// Strategy: per-level fused kernel -- LDS tile (32x32 + halo 5) of img1/img2,
// separable conv (horizontal pass -> 5 LDS planes -> vertical pass), per-pixel
// SSIM/MCS, block reduction to per-block partials in ws (no atomics), pooled
// next-level images written from the staged LDS tile. Final 1-block kernel
// reduces partials and emits the scalar.

#define TS 32
#define HALO 5
#define TP (TS + 2 * HALO)  // 42
#define WS 11

__global__ __launch_bounds__(256) void ssim_level_kernel(
    const float* __restrict__ img1, const float* __restrict__ img2,
    int H, int W,
    float* __restrict__ pool1, float* __restrict__ pool2,  // null on last level
    float* __restrict__ partials)                           // 2 floats per block
{
    __shared__ float s1[TP][TP];
    __shared__ float s2[TP][TP];
    __shared__ float hA[TP][TS], hB[TP][TS], hAA[TP][TS], hBB[TP][TS], hAB[TP][TS];
    __shared__ float wg[WS];
    __shared__ float red[2][4];

    const int tid = threadIdx.x;

    // Gaussian window: computed in double, normalized, cast to f32 (matches ref).
    if (tid == 0) {
        double g[WS];
        double s = 0.0;
        for (int i = 0; i < WS; ++i) {
            double d = (double)(i - WS / 2);
            g[i] = exp(-(d * d) / (2.0 * 1.5 * 1.5));
            s += g[i];
        }
        for (int i = 0; i < WS; ++i) wg[i] = (float)(g[i] / s);
    }

    const int tx = blockIdx.x, ty = blockIdx.y, b = blockIdx.z;
    const int x0 = tx * TS - HALO, y0 = ty * TS - HALO;
    const float* p1 = img1 + (size_t)b * H * W;
    const float* p2 = img2 + (size_t)b * H * W;

    // Stage tiles with zero-padded halo.
    for (int idx = tid; idx < TP * TP; idx += 256) {
        int yy = idx / TP, xx = idx % TP;
        int gy = y0 + yy, gx = x0 + xx;
        float v1 = 0.f, v2 = 0.f;
        if (gy >= 0 && gy < H && gx >= 0 && gx < W) {
            v1 = p1[(size_t)gy * W + gx];
            v2 = p2[(size_t)gy * W + gx];
        }
        s1[yy][xx] = v1;
        s2[yy][xx] = v2;
    }
    __syncthreads();

    // Fused 2x2 avg-pool for the next level (tile is 32x32 -> 16x16 pooled).
    if (pool1 != nullptr) {
        int py = tid >> 4, px = tid & 15;   // 256 threads == 16*16 outputs
        int Hp = H >> 1, Wp = W >> 1;
        int sy = HALO + 2 * py, sx = HALO + 2 * px;
        float a = 0.25f * (s1[sy][sx] + s1[sy][sx + 1] + s1[sy + 1][sx] + s1[sy + 1][sx + 1]);
        float c = 0.25f * (s2[sy][sx] + s2[sy][sx + 1] + s2[sy + 1][sx] + s2[sy + 1][sx + 1]);
        size_t o = ((size_t)b * Hp + (ty * 16 + py)) * Wp + (tx * 16 + px);
        pool1[o] = a;
        pool2[o] = c;
    }

    // Stage 1: horizontal 11-tap pass over (TP rows x TS cols).
    for (int idx = tid; idx < TP * TS; idx += 256) {
        int yy = idx / TS, xx = idx % TS;
        float a = 0.f, bv = 0.f, aa = 0.f, bb = 0.f, ab = 0.f;
#pragma unroll
        for (int j = 0; j < WS; ++j) {
            float w = wg[j];
            float v1 = s1[yy][xx + j];
            float v2 = s2[yy][xx + j];
            float t1 = w * v1, t2 = w * v2;
            a += t1;
            bv += t2;
            aa = fmaf(t1, v1, aa);
            bb = fmaf(t2, v2, bb);
            ab = fmaf(t1, v2, ab);
        }
        hA[yy][xx] = a;
        hB[yy][xx] = bv;
        hAA[yy][xx] = aa;
        hBB[yy][xx] = bb;
        hAB[yy][xx] = ab;
    }
    __syncthreads();

    // Stage 2: vertical 11-tap pass + SSIM/MCS per pixel.
    const float C1 = 6.5025f;    // (0.01*255)^2
    const float C2 = 58.5225f;   // (0.03*255)^2
    float ssim_acc = 0.f, mcs_acc = 0.f;
    for (int idx = tid; idx < TS * TS; idx += 256) {
        int yy = idx >> 5, xx = idx & 31;
        float mu1 = 0.f, mu2 = 0.f, sAA = 0.f, sBB = 0.f, sAB = 0.f;
#pragma unroll
        for (int j = 0; j < WS; ++j) {
            float w = wg[j];
            mu1 = fmaf(w, hA[yy + j][xx], mu1);
            mu2 = fmaf(w, hB[yy + j][xx], mu2);
            sAA = fmaf(w, hAA[yy + j][xx], sAA);
            sBB = fmaf(w, hBB[yy + j][xx], sBB);
            sAB = fmaf(w, hAB[yy + j][xx], sAB);
        }
        float mu1s = mu1 * mu1, mu2s = mu2 * mu2, mu12 = mu1 * mu2;
        float sig1 = sAA - mu1s, sig2 = sBB - mu2s, sig12 = sAB - mu12;
        float V1 = 2.f * sig12 + C2;
        float V2 = sig1 + sig2 + C2;
        float ssim = (2.f * mu12 + C1) * V1 / ((mu1s + mu2s + C1) * V2);
        float mcs = V1 / V2;
        ssim_acc += ssim;
        mcs_acc += mcs;
    }

    // Block reduction: wave64 shuffle then cross-wave via LDS.
#pragma unroll
    for (int o = 32; o > 0; o >>= 1) {
        ssim_acc += __shfl_down(ssim_acc, o);
        mcs_acc += __shfl_down(mcs_acc, o);
    }
    int wave = tid >> 6, lane = tid & 63;
    if (lane == 0) {
        red[0][wave] = ssim_acc;
        red[1][wave] = mcs_acc;
    }
    __syncthreads();
    if (tid == 0) {
        float s = red[0][0] + red[0][1] + red[0][2] + red[0][3];
        float m = red[1][0] + red[1][1] + red[1][2] + red[1][3];
        size_t linear = ((size_t)blockIdx.z * gridDim.y + blockIdx.y) * gridDim.x + blockIdx.x;
        partials[2 * linear] = s;
        partials[2 * linear + 1] = m;
    }
}

__global__ __launch_bounds__(256) void finalize_kernel(
    const float* __restrict__ partials, float* __restrict__ out)
{
    __shared__ float lvl_s[5], lvl_m[5];
    __shared__ float red[2][4];
    const int nb[5] = {4096, 1024, 256, 64, 16};
    const int off[5] = {0, 4096, 5120, 5376, 5440};
    const float npix[5] = {16.f * 512 * 512, 16.f * 256 * 256, 16.f * 128 * 128,
                           16.f * 64 * 64, 16.f * 32 * 32};
    const int tid = threadIdx.x;

    for (int l = 0; l < 5; ++l) {
        float s = 0.f, m = 0.f;
        for (int i = tid; i < nb[l]; i += 256) {
            s += partials[2 * (off[l] + i)];
            m += partials[2 * (off[l] + i) + 1];
        }
#pragma unroll
        for (int o = 32; o > 0; o >>= 1) {
            s += __shfl_down(s, o);
            m += __shfl_down(m, o);
        }
        int wave = tid >> 6, lane = tid & 63;
        if (lane == 0) {
            red[0][wave] = s;
            red[1][wave] = m;
        }
        __syncthreads();
        if (tid == 0) {
            lvl_s[l] = (red[0][0] + red[0][1] + red[0][2] + red[0][3]) / npix[l];
            lvl_m[l] = (red[1][0] + red[1][1] + red[1][2] + red[1][3]) / npix[l];
        }
        __syncthreads();
    }

    if (tid == 0) {
        const float w[5] = {0.0448f, 0.2856f, 0.3001f, 0.2363f, 0.1333f};
        float v = powf(lvl_m[0], w[0]) * powf(lvl_m[1], w[1]) * powf(lvl_m[2], w[2]) *
                  powf(lvl_m[3], w[3]) * powf(lvl_s[4], w[4]);
        v *= 0.5f;
        v = fminf(fmaxf(v, 0.f), 1.f);
        out[0] = v;
    }
}

extern "C" void kernel_launch(void* const* d_in, const int* in_sizes, int n_in,
                              void* d_out, int out_size, void* d_ws, size_t ws_size,
                              hipStream_t stream) {
    const float* img1 = (const float*)d_in[0];
    const float* img2 = (const float*)d_in[1];
    float* out = (float*)d_out;

    const int B = 16;

    // Workspace layout (floats):
    //   partials: 5456 blocks * 2 = 10912 floats
    //   pooled image pairs for levels 1..4
    float* wsf = (float*)d_ws;
    float* partials = wsf;
    float* p = wsf + 10912;
    float* p1_l1 = p; p += (size_t)B * 256 * 256;
    float* p2_l1 = p; p += (size_t)B * 256 * 256;
    float* p1_l2 = p; p += (size_t)B * 128 * 128;
    float* p2_l2 = p; p += (size_t)B * 128 * 128;
    float* p1_l3 = p; p += (size_t)B * 64 * 64;
    float* p2_l3 = p; p += (size_t)B * 64 * 64;
    float* p1_l4 = p; p += (size_t)B * 32 * 32;
    float* p2_l4 = p; p += (size_t)B * 32 * 32;

    const int part_off[5] = {0, 4096, 5120, 5376, 5440};

    dim3 block(256);

    // Level 0: 512x512
    ssim_level_kernel<<<dim3(16, 16, B), block, 0, stream>>>(
        img1, img2, 512, 512, p1_l1, p2_l1, partials + 2 * part_off[0]);
    // Level 1: 256x256
    ssim_level_kernel<<<dim3(8, 8, B), block, 0, stream>>>(
        p1_l1, p2_l1, 256, 256, p1_l2, p2_l2, partials + 2 * part_off[1]);
    // Level 2: 128x128
    ssim_level_kernel<<<dim3(4, 4, B), block, 0, stream>>>(
        p1_l2, p2_l2, 128, 128, p1_l3, p2_l3, partials + 2 * part_off[2]);
    // Level 3: 64x64
    ssim_level_kernel<<<dim3(2, 2, B), block, 0, stream>>>(
        p1_l3, p2_l3, 64, 64, p1_l4, p2_l4, partials + 2 * part_off[3]);
    // Level 4: 32x32 (no pooling output)
    ssim_level_kernel<<<dim3(1, 1, B), block, 0, stream>>>(
        p1_l4, p2_l4, 32, 32, nullptr, nullptr, partials + 2 * part_off[4]);

    finalize_kernel<<<1, block, 0, stream>>>(partials, out);
}